// Round 8
// baseline (589.222 us; speedup 1.0000x reference)
//
#include <hip/hip_runtime.h>
#include <hip/hip_bf16.h>
#include <stdint.h>

#define BDIM 8192
#define HDIM 2048
#define KDIM 4096   // IN + H
#define NDIM 6144   // 3 * H

using f32x4  = __attribute__((ext_vector_type(4))) float;
using bf16x8 = __attribute__((ext_vector_type(8))) short;

__device__ __forceinline__ uint16_t f2bf(float f) {
    union { float f; uint32_t u; } v;
    v.f = f;
    uint32_t r = v.u + 0x7fffu + ((v.u >> 16) & 1u);  // RNE
    return (uint16_t)(r >> 16);
}

__device__ __forceinline__ float fast_sigmoid(float x) {
    return 1.0f / (1.0f + __expf(-x));
}

__device__ __forceinline__ float fast_tanh(float x) {
    float ax = fabsf(x);
    float t = __expf(-2.0f * ax);
    float r = (1.0f - t) / (1.0f + t);
    return copysignf(r, x);
}

// ---------------- fused conversion kernel ----------------
// xh = concat(x,h) -> bf16 [8192][4096]
// Wb = gate-interleaved weights -> bf16 [6144][4096]:
//   out row for (gate g, h) = (h>>4)*48 + g*16 + (h&15)
#define XH_CHUNKS ((int64_t)BDIM * KDIM / 4)
#define W_CHUNKS  ((int64_t)3 * HDIM * KDIM / 4)

__global__ void cvt_all_kernel(const float* __restrict__ x,
                               const float* __restrict__ h,
                               const float* __restrict__ Wf,
                               const float* __restrict__ Wo,
                               const float* __restrict__ Wc,
                               uint16_t* __restrict__ xh,
                               uint16_t* __restrict__ Wb) {
    const int64_t total = XH_CHUNKS + W_CHUNKS;
    for (int64_t i = (int64_t)blockIdx.x * blockDim.x + threadIdx.x; i < total;
         i += (int64_t)gridDim.x * blockDim.x) {
        float4 v;
        uint16_t* dst;
        if (i < XH_CHUNKS) {
            int64_t e = i << 2;
            int b = (int)(e >> 12);
            int k = (int)(e & 4095);
            if (k < 2048) v = *(const float4*)(x + (int64_t)b * 2048 + k);
            else          v = *(const float4*)(h + (int64_t)b * 2048 + (k - 2048));
            dst = xh + e;
        } else {
            int64_t e = (i - XH_CHUNKS) << 2;
            const int64_t per_gate = (int64_t)HDIM * KDIM;
            int gate = (int)(e / per_gate);
            int64_t rem = e - (int64_t)gate * per_gate;
            const float* src = (gate == 0) ? Wf : (gate == 1) ? Wo : Wc;
            v = *(const float4*)(src + rem);
            const int hrow = (int)(rem >> 12);
            const int k = (int)(rem & 4095);
            const int orow = ((hrow >> 4) * 48) + (gate << 4) + (hrow & 15);
            dst = Wb + (int64_t)orow * KDIM + k;
        }
        ushort4 o;
        o.x = f2bf(v.x); o.y = f2bf(v.y); o.z = f2bf(v.z); o.w = f2bf(v.w);
        *(ushort4*)dst = o;
    }
}

// ------------- 256x192 4-phase GEMM with fused LSTM epilogue -------------
// A: [8192][4096] bf16; Wb: [6144][4096] bf16 gate-interleaved (B^T).
// Tile: BM=256, BN=192 (= 64 h-cols x 3 gates). Grid 32x32=1024 blocks.
// 8 waves (2M x 4N): per wave C = 128 rows x 48 cols (16 h-cols x 3 gates)
//   -> acc[8][3] (AM=qm*4+mf, gate). BK=64.
// LDS: ldsA 4 slots x 16 KiB (A-halves, layout identical to rounds 2-7),
//      ldsB 2 slots x 24 KiB (192 rows x 64 cols; staged as 3 x 64-row
//      sections, 1 chunk/thread each). Total 112 KiB.
// Phases per iter (t0 even, t1 odd; 2 K-tiles):
//   Q1: rd aF(A0e: t0 h0)[8] + bF(Be: t0)[6]; stage A1o<-A(t1,h1);
//       MM(qm=0, g=0..2) [24 MFMA]; WC7; bar
//   Q2: rd aF(A1e: t0 h1)[8]; stage A0e<-A(t2,h0), Be<-B(t2)[3];
//       MM(qm=1, g=0..2); WC7; bar
//   Q3: rd aF(A0o: t1 h0)[8] + bF(Bo: t1)[6]; stage A1e<-A(t2,h1);
//       MM(0,*); WC7; bar
//   Q4: rd aF(A1o: t1 h1)[8]; stage A0o<-A(t3,h0), Bo<-B(t3)[3];
//       MM(1,*); WC7; bar
// FIFO proof (7 loads/iter-half; WC7 at each phase end):
//   invariant entering Q1: outstanding = {A1e'(2), A0o'(2), Bo'(3)} (7).
//   Q1 reads A0e,Be (staged pQ2, older than the 7 -> complete). +A1o(2)=9;
//     WC7 completes A1e' -> Q2 read OK. leaves {A0o',Bo',A1o}.
//   Q2 +A0e(2),Be(3)=12; WC7 completes A0o',Bo' -> Q3 read OK.
//   Q3 reads A0o',Bo' OK. +A1e(2)=9; WC7 completes A1o -> Q4 read OK.
//   Q4 reads A1o OK. +A0o(2),Bo(3)=12; WC7 completes A0e,Be -> next Q1 OK;
//     leaves {A1e,A0o,Bo} = invariant. QED.
// Re-stage safety: every slot staged >=1 barrier-phase after its last read.

#define STAGE_A(slot, t, h) do { \
    _Pragma("unroll") for (int q_ = 0; q_ < 2; ++q_) { \
        const int r_ = s_row[q_]; \
        const uint16_t* src_ = A + (int64_t)(m0 + ((r_ >> 6) << 7) + ((h) << 6) + (r_ & 63)) * KDIM + ((t) << 6) + s_kc[q_]; \
        __builtin_amdgcn_global_load_lds((__attribute__((address_space(1))) void*)(src_), \
            (__attribute__((address_space(3))) void*)(&ldsA[slot][(q_ * 512 + tid) * 8]), 16, 0, 0); \
    } } while (0)

#define STAGE_B3(slot, t) do { \
    _Pragma("unroll") for (int sec_ = 0; sec_ < 3; ++sec_) { \
        const uint16_t* src_ = Wb + (int64_t)(n0r + sec_ * 64 + s_row[0]) * KDIM + ((t) << 6) + s_kc[0]; \
        __builtin_amdgcn_global_load_lds((__attribute__((address_space(1))) void*)(src_), \
            (__attribute__((address_space(3))) void*)(&ldsB[slot][(sec_ * 512 + tid) * 8]), 16, 0, 0); \
    } } while (0)

#define RDA(slot, srow, kc) \
    (*(const bf16x8*)((const char*)(&ldsA[0][0]) + ((slot) * 16384) + ((srow) * 128) + ((((kc) ^ ((srow) & 7))) * 16)))
#define RDB(slot, srow, kc) \
    (*(const bf16x8*)((const char*)(&ldsB[0][0]) + ((slot) * 24576) + ((srow) * 128) + ((((kc) ^ ((srow) & 7))) * 16)))

#define RD_A(tp, h) do { \
    _Pragma("unroll") for (int kk = 0; kk < 2; ++kk) \
        _Pragma("unroll") for (int mf = 0; mf < 4; ++mf) \
            aF[kk][mf] = RDA((((tp) & 1) << 1) + (h), wm * 64 + mf * 16 + fr, kk * 4 + kg); \
} while (0)

#define RD_B3(tp) do { \
    _Pragma("unroll") for (int kk = 0; kk < 2; ++kk) \
        _Pragma("unroll") for (int gt = 0; gt < 3; ++gt) \
            bF[kk][gt] = RDB((tp) & 1, wn * 48 + gt * 16 + fr, kk * 4 + kg); \
} while (0)

#define MMQ(qm) do { \
    _Pragma("unroll") for (int kk = 0; kk < 2; ++kk) \
        _Pragma("unroll") for (int mf = 0; mf < 4; ++mf) \
            _Pragma("unroll") for (int gt = 0; gt < 3; ++gt) \
                acc[(qm) * 4 + mf][gt] = __builtin_amdgcn_mfma_f32_16x16x32_bf16( \
                    aF[kk][mf], bF[kk][gt], acc[(qm) * 4 + mf][gt], 0, 0, 0); \
} while (0)

#define PHF(READS, STAGE, MMS, WAITC) do { \
    asm volatile("" ::: "memory"); \
    READS; \
    STAGE; \
    asm volatile("" ::: "memory"); \
    __builtin_amdgcn_s_setprio(1); \
    MMS; \
    __builtin_amdgcn_s_setprio(0); \
    WAITC; \
    __builtin_amdgcn_s_barrier(); \
} while (0)

#define WC7 asm volatile("s_waitcnt vmcnt(7)" ::: "memory")
#define WC0 asm volatile("s_waitcnt vmcnt(0)" ::: "memory")

__global__ __launch_bounds__(512, 2) void lstm_gemm_fused_kernel(
    const uint16_t* __restrict__ A,
    const uint16_t* __restrict__ Wb,
    const float* __restrict__ c_prev,
    const float* __restrict__ b_f,
    const float* __restrict__ b_o,
    const float* __restrict__ b_c,
    float* __restrict__ h_out,
    float* __restrict__ c_out) {
    __shared__ uint16_t ldsA[4][8192];   // 64 KiB
    __shared__ uint16_t ldsB[2][12288];  // 48 KiB

    const int tid = threadIdx.x;
    const int lane = tid & 63;
    const int kg = lane >> 4;
    const int fr = lane & 15;
    const int wid = tid >> 6;
    const int wm = wid >> 2;   // 0..1
    const int wn = wid & 3;    // 0..3

    // XCD-aware swizzle: 1024 blocks, 1024 % 8 == 0 -> simple bijection
    const int bid = blockIdx.x;
    const int swz = (bid & 7) * 128 + (bid >> 3);
    const int mb = swz >> 5;          // 0..31
    const int nb = swz & 31;          // 0..31
    const int m0 = mb << 8;           // 256-row tile
    const int n0r = nb * 192;         // Wb row base (interleaved)
    const int n0h = nb << 6;          // h-col base

    // staging constants: chunk = q*512 + tid -> row, swizzled k-offset
    int s_row[2], s_kc[2];
#pragma unroll
    for (int q_ = 0; q_ < 2; ++q_) {
        const int chunk = q_ * 512 + tid;
        const int r_ = chunk >> 3;
        const int c_ = chunk & 7;
        s_row[q_] = r_;
        s_kc[q_] = (c_ ^ (r_ & 7)) * 8;  // element offset
    }

    f32x4 acc[8][3] = {};
    bf16x8 aF[2][4];
    bf16x8 bF[2][3];

    // prologue FIFO (oldest->newest): A0e(2), Be(3), A1e(2), A0o(2), Bo(3)
    STAGE_A(0, 0, 0);       // A0e <- t0 h0
    STAGE_B3(0, 0);         // Be  <- t0
    STAGE_A(1, 0, 1);       // A1e <- t0 h1
    STAGE_A(2, 1, 0);       // A0o <- t1 h0
    STAGE_B3(1, 1);         // Bo  <- t1
    WC7;  // completes A0e,Be; leaves {A1e,A0o,Bo} = steady-state invariant
    __builtin_amdgcn_s_barrier();

    // 64 K-tiles, 2 per iteration; i=31 peeled as tail
    for (int i = 0; i < 31; ++i) {
        const int t0 = 2 * i;
        const int t1 = t0 + 1, t2 = t0 + 2, t3 = t0 + 3;
        PHF(RD_A(t0, 0); RD_B3(t0), STAGE_A(3, t1, 1),               MMQ(0), WC7);
        PHF(RD_A(t0, 1),            STAGE_A(0, t2, 0); STAGE_B3(0, t2), MMQ(1), WC7);
        PHF(RD_A(t1, 0); RD_B3(t1), STAGE_A(1, t2, 1),               MMQ(0), WC7);
        PHF(RD_A(t1, 1),            STAGE_A(2, t3, 0); STAGE_B3(1, t3), MMQ(1), WC7);
    }
    // tail: t0=62, t1=63; only A1o<-A(63,h1) remains in-range
    PHF(RD_A(62, 0); RD_B3(62), STAGE_A(3, 63, 1), MMQ(0), WC7);
    PHF(RD_A(62, 1),            ;,                 MMQ(1), WC0);
    PHF(RD_A(63, 0); RD_B3(63), ;,                 MMQ(0), );
    PHF(RD_A(63, 1),            ;,                 MMQ(1), );

    // ---- fused LSTM epilogue ----
    // D layout: col = lane&15 = fr, row = kg*4 + j within each 16x16 frag.
    const int hcol = n0h + wn * 16 + fr;
    const float bfv = b_f[hcol];
    const float bov = b_o[hcol];
    const float bcv = b_c[hcol];
#pragma unroll
    for (int AM = 0; AM < 8; ++AM) {
        const int mbase = m0 + wm * 128 + AM * 16 + kg * 4;
#pragma unroll
        for (int j = 0; j < 4; ++j) {
            const int64_t moff = (int64_t)(mbase + j) * HDIM + hcol;
            const float fpre = acc[AM][0][j] + bfv;
            const float opre = acc[AM][1][j] + bov;
            const float cpre = acc[AM][2][j] + bcv;
            const float ft = fast_sigmoid(fpre);
            const float ot = fast_sigmoid(opre);
            const float ch = fast_tanh(cpre);
            const float cp = c_prev[moff];
            const float ct = ft * cp + (1.0f - ft) * ch;
            h_out[moff] = ot * fast_tanh(ct);
            c_out[moff] = ct;
        }
    }
}

extern "C" void kernel_launch(void* const* d_in, const int* in_sizes, int n_in,
                              void* d_out, int out_size, void* d_ws, size_t ws_size,
                              hipStream_t stream) {
    const float* x_t   = (const float*)d_in[0];
    const float* h_t_1 = (const float*)d_in[1];
    const float* c_t_1 = (const float*)d_in[2];
    const float* W_f   = (const float*)d_in[3];
    const float* b_f   = (const float*)d_in[4];
    const float* W_o   = (const float*)d_in[5];
    const float* b_o   = (const float*)d_in[6];
    const float* W_c   = (const float*)d_in[7];
    const float* b_c   = (const float*)d_in[8];

    uint16_t* xh  = (uint16_t*)d_ws;                            // 64 MiB
    uint16_t* Wbf = xh + (size_t)BDIM * KDIM;                   // 48 MiB

    float* h_out = (float*)d_out;
    float* c_out = h_out + (size_t)BDIM * HDIM;

    cvt_all_kernel<<<2048, 256, 0, stream>>>(x_t, h_t_1, W_f, W_o, W_c, xh, Wbf);
    lstm_gemm_fused_kernel<<<1024, 512, 0, stream>>>(xh, Wbf, c_t_1,
                                                     b_f, b_o, b_c,
                                                     h_out, c_out);
}

// Round 10
// 493.143 us; speedup vs baseline: 1.1948x; 1.1948x over previous
//
#include <hip/hip_runtime.h>
#include <hip/hip_bf16.h>
#include <stdint.h>

#define BDIM 8192
#define HDIM 2048
#define KDIM 4096   // IN + H
#define NDIM 6144   // 3 * H

using f32x4  = __attribute__((ext_vector_type(4))) float;
using bf16x8 = __attribute__((ext_vector_type(8))) short;
using short8 = __attribute__((ext_vector_type(8))) short;

__device__ __forceinline__ uint16_t f2bf(float f) {
    union { float f; uint32_t u; } v;
    v.f = f;
    uint32_t r = v.u + 0x7fffu + ((v.u >> 16) & 1u);  // RNE
    return (uint16_t)(r >> 16);
}

__device__ __forceinline__ float bf2f(uint16_t u) {
    union { uint32_t u; float f; } v;
    v.u = ((uint32_t)u) << 16;
    return v.f;
}

__device__ __forceinline__ float fast_sigmoid(float x) {
    return 1.0f / (1.0f + __expf(-x));
}

__device__ __forceinline__ float fast_tanh(float x) {
    float ax = fabsf(x);
    float t = __expf(-2.0f * ax);
    float r = (1.0f - t) / (1.0f + t);
    return copysignf(r, x);
}

__device__ __forceinline__ short8 cvt8(f32x4 a, f32x4 b) {
    short8 o;
    o[0] = (short)f2bf(a[0]); o[1] = (short)f2bf(a[1]);
    o[2] = (short)f2bf(a[2]); o[3] = (short)f2bf(a[3]);
    o[4] = (short)f2bf(b[0]); o[5] = (short)f2bf(b[1]);
    o[6] = (short)f2bf(b[2]); o[7] = (short)f2bf(b[3]);
    return o;
}

// ---------------- fused conversion kernel (8 elems/thread/iter) ----------
// xh = concat(x,h) -> bf16 [8192][4096]; Wb = [W_f;W_o;W_c] -> bf16 [6144][4096]
#define XH_CH8 ((int64_t)BDIM * KDIM / 8)
#define W_CH8  ((int64_t)3 * HDIM * KDIM / 8)
#define PER_GATE ((int64_t)HDIM * KDIM)

__global__ void cvt_all_kernel(const float* __restrict__ x,
                               const float* __restrict__ h,
                               const float* __restrict__ Wf,
                               const float* __restrict__ Wo,
                               const float* __restrict__ Wc,
                               uint16_t* __restrict__ xh,
                               uint16_t* __restrict__ Wb) {
    const int64_t total = XH_CH8 + W_CH8;
    for (int64_t i = (int64_t)blockIdx.x * blockDim.x + threadIdx.x; i < total;
         i += (int64_t)gridDim.x * blockDim.x) {
        const float* src;
        uint16_t* dst;
        if (i < XH_CH8) {
            int64_t e = i << 3;
            int b = (int)(e >> 12);
            int k = (int)(e & 4095);
            src = (k < 2048) ? (x + (int64_t)b * 2048 + k)
                             : (h + (int64_t)b * 2048 + (k - 2048));
            dst = xh + e;
        } else {
            int64_t e = (i - XH_CH8) << 3;
            // gate select without 64-bit division
            int gate = (e >= 2 * PER_GATE) ? 2 : (e >= PER_GATE ? 1 : 0);
            int64_t rem = e - (int64_t)gate * PER_GATE;
            const float* w = (gate == 0) ? Wf : (gate == 1) ? Wo : Wc;
            src = w + rem;
            dst = Wb + e;
        }
        f32x4 v0 = *(const f32x4*)(src);
        f32x4 v1 = *(const f32x4*)(src + 4);
        *(short8*)dst = cvt8(v0, v1);
    }
}

// ---------------- 256x256 4-phase GEMM (32 MFMA / barrier) ---------------
// Round-7 kernel verbatim (best measured: 327 us, MfmaUtil 58%, 0 conflicts).
// 8 waves (2M x 4N), per-wave C = 128x64. BK=64. 8-slot LDS ring (128 KiB).
//   A slots: even tile h0->0 h1->1, odd tile h0->2 h1->3
//   B slots: even tile h0->4 h1->5, odd tile h0->6 h1->7
// 4 phases per iteration (2 K-tiles t0,t1), fragment-reuse, split MM in
// Q2/Q4 to recycle bF0 registers. WC4@Q2 and WC4@Q4 cover all reads
// (FIFO proof in round-6/7 journals). 2 waits + 4 barriers / 2 K-tiles.

#define STAGE_A(slot, t, h) do { \
    _Pragma("unroll") for (int q_ = 0; q_ < 2; ++q_) { \
        const int r_ = s_row[q_]; \
        const uint16_t* src_ = A + (int64_t)(m0 + ((r_ >> 6) << 7) + ((h) << 6) + (r_ & 63)) * KDIM + ((t) << 6) + s_kc[q_]; \
        __builtin_amdgcn_global_load_lds((__attribute__((address_space(1))) void*)(src_), \
            (__attribute__((address_space(3))) void*)(&lds[slot][(q_ * 512 + tid) * 8]), 16, 0, 0); \
    } } while (0)

#define STAGE_B(slot, t, h) do { \
    _Pragma("unroll") for (int q_ = 0; q_ < 2; ++q_) { \
        const int r_ = s_row[q_]; \
        const uint16_t* src_ = Wb + (int64_t)(n0 + ((r_ >> 5) << 6) + ((h) << 5) + (r_ & 31)) * KDIM + ((t) << 6) + s_kc[q_]; \
        __builtin_amdgcn_global_load_lds((__attribute__((address_space(1))) void*)(src_), \
            (__attribute__((address_space(3))) void*)(&lds[slot][(q_ * 512 + tid) * 8]), 16, 0, 0); \
    } } while (0)

// read logical (slot, srow, kchunk) with swizzle
#define RD(slot, srow, kc) \
    (*(const bf16x8*)((const char*)(&lds[0][0]) + ((slot) * 16384) + ((srow) * 128) + ((((kc) ^ ((srow) & 7))) * 16)))

#define RD_A(tp, h) do { \
    _Pragma("unroll") for (int kk = 0; kk < 2; ++kk) \
        _Pragma("unroll") for (int mf = 0; mf < 4; ++mf) \
            aF[kk][mf] = RD((((tp) & 1) << 1) + (h), wm * 64 + mf * 16 + fr, kk * 4 + kg); \
} while (0)

#define RD_B(dst, tp, h) do { \
    _Pragma("unroll") for (int kk = 0; kk < 2; ++kk) \
        _Pragma("unroll") for (int nf = 0; nf < 2; ++nf) \
            dst[kk][nf] = RD(4 + (((tp) & 1) << 1) + (h), wn * 32 + nf * 16 + fr, kk * 4 + kg); \
} while (0)

#define MM(qm, qn, bsrc) do { \
    _Pragma("unroll") for (int kk = 0; kk < 2; ++kk) \
        _Pragma("unroll") for (int mf = 0; mf < 4; ++mf) \
            _Pragma("unroll") for (int nf = 0; nf < 2; ++nf) \
                acc[(qm) * 4 + mf][(qn) * 2 + nf] = __builtin_amdgcn_mfma_f32_16x16x32_bf16( \
                    aF[kk][mf], bsrc[kk][nf], acc[(qm) * 4 + mf][(qn) * 2 + nf], 0, 0, 0); \
} while (0)

#define PH4(READS1, STAGE, MM1, READS2, MM2, WAITC) do { \
    asm volatile("" ::: "memory"); \
    READS1; \
    STAGE; \
    asm volatile("" ::: "memory"); \
    __builtin_amdgcn_s_setprio(1); \
    MM1; \
    __builtin_amdgcn_s_setprio(0); \
    asm volatile("" ::: "memory"); \
    READS2; \
    asm volatile("" ::: "memory"); \
    __builtin_amdgcn_s_setprio(1); \
    MM2; \
    __builtin_amdgcn_s_setprio(0); \
    WAITC; \
    __builtin_amdgcn_s_barrier(); \
} while (0)

#define WC4 asm volatile("s_waitcnt vmcnt(4)" ::: "memory")
#define WC0 asm volatile("s_waitcnt vmcnt(0)" ::: "memory")

__global__ __launch_bounds__(512, 2) void lstm_gemm4p_kernel(
    const uint16_t* __restrict__ A,
    const uint16_t* __restrict__ Wb,
    uint16_t* __restrict__ G) {
    __shared__ uint16_t lds[8][8192];  // 128 KiB

    const int tid = threadIdx.x;
    const int lane = tid & 63;
    const int kg = lane >> 4;
    const int fr = lane & 15;
    const int wid = tid >> 6;
    const int wm = wid >> 2;   // 0..1
    const int wn = wid & 3;    // 0..3

    // XCD-aware swizzle: 768 blocks, 768 % 8 == 0 -> simple bijection
    const int bid = blockIdx.x;
    const int swz = (bid & 7) * 96 + (bid >> 3);
    const int mb = swz / 24;
    const int nb = swz - mb * 24;
    const int m0 = mb << 8;
    const int n0 = nb << 8;

    // staging constants: chunk = q*512 + tid -> row, swizzled k-chunk
    int s_row[2], s_kc[2];
#pragma unroll
    for (int q_ = 0; q_ < 2; ++q_) {
        const int chunk = q_ * 512 + tid;
        const int r_ = chunk >> 3;
        const int c_ = chunk & 7;
        s_row[q_] = r_;
        s_kc[q_] = (c_ ^ (r_ & 7)) * 8;  // element offset
    }

    f32x4 acc[8][4] = {};
    bf16x8 aF[2][4];
    bf16x8 bF0[2][2];
    bf16x8 bF1[2][2];

    // prologue: s4(B0h0),s0(A0h0),s5(B0h1),s1(A0h1),s6(B1h0) must complete;
    // s2(A1h0),s7(B1h1) may stay in flight (covered by WC4@Q2 of iter 0).
    STAGE_B(4, 0, 0); STAGE_A(0, 0, 0); STAGE_B(5, 0, 1);
    STAGE_A(1, 0, 1); STAGE_B(6, 1, 0);
    STAGE_A(2, 1, 0); STAGE_B(7, 1, 1);
    WC4;  // completes s4,s0,s5,s1,s6; leaves s2,s7 in flight
    __builtin_amdgcn_s_barrier();
    RD_B(bF0, 0, 0);  // pre-read B(0,h0) from s4
    asm volatile("s_waitcnt lgkmcnt(0)" ::: "memory");
    __builtin_amdgcn_s_barrier();  // s4 safe to re-stage from Q1 on

    // 64 K-tiles, 2 per iteration; i=31 is the peeled tail
    for (int i = 0; i < 31; ++i) {
        const int t0 = 2 * i;
        const int t1 = t0 + 1, t2 = t0 + 2, t3 = t0 + 3;
        PH4(RD_A(t0, 0); RD_B(bF1, t0, 1),
            STAGE_A(3, t1, 1); STAGE_B(4, t2, 0),
            MM(0, 0, bF0); MM(0, 1, bF1), ;, ;, );
        PH4(RD_A(t0, 1),
            STAGE_A(0, t2, 0); STAGE_B(5, t2, 1),
            MM(1, 0, bF0), RD_B(bF0, t1, 0), MM(1, 1, bF1), WC4);
        PH4(RD_A(t1, 0); RD_B(bF1, t1, 1),
            STAGE_A(1, t2, 1); STAGE_B(6, t3, 0),
            MM(0, 0, bF0); MM(0, 1, bF1), ;, ;, );
        PH4(RD_A(t1, 1),
            STAGE_A(2, t3, 0); STAGE_B(7, t3, 1),
            MM(1, 0, bF0), RD_B(bF0, t2, 0), MM(1, 1, bF1), WC4);
    }
    // tail: t0=62, t1=63; stages beyond K dropped; WC0 drains {s2,s7,s3}
    PH4(RD_A(62, 0); RD_B(bF1, 62, 1),
        STAGE_A(3, 63, 1),
        MM(0, 0, bF0); MM(0, 1, bF1), ;, ;, );
    PH4(RD_A(62, 1), ;,
        MM(1, 0, bF0), RD_B(bF0, 63, 0), MM(1, 1, bF1), WC0);
    PH4(RD_A(63, 0); RD_B(bF1, 63, 1), ;,
        MM(0, 0, bF0); MM(0, 1, bF1), ;, ;, );
    PH4(RD_A(63, 1), ;,
        MM(1, 0, bF0), ;, MM(1, 1, bF1), );

    // C-write: D layout col = lane&15, row = (lane>>4)*4 + j
#pragma unroll
    for (int mf = 0; mf < 8; ++mf) {
#pragma unroll
        for (int nf = 0; nf < 4; ++nf) {
            const int n = n0 + wn * 64 + nf * 16 + fr;
            const int64_t mbase = (int64_t)(m0 + wm * 128 + mf * 16 + kg * 4);
#pragma unroll
            for (int j = 0; j < 4; ++j) {
                G[(mbase + j) * NDIM + n] = f2bf(acc[mf][nf][j]);
            }
        }
    }
}

// ---------------- LSTM elementwise epilogue (non-temporal I/O) ----------

__global__ void lstm_epi_kernel(const uint16_t* __restrict__ G,
                                const float* __restrict__ c_prev,
                                const float* __restrict__ b_f,
                                const float* __restrict__ b_o,
                                const float* __restrict__ b_c,
                                float* __restrict__ h_out,
                                float* __restrict__ c_out) {
    const int64_t total = (int64_t)BDIM * HDIM / 8;
    for (int64_t i = (int64_t)blockIdx.x * blockDim.x + threadIdx.x; i < total;
         i += (int64_t)gridDim.x * blockDim.x) {
        const int64_t e = i << 3;
        const int m = (int)(e >> 11);
        const int n = (int)(e & 2047);
        const int64_t gb = (int64_t)m * NDIM + n;
        const short8 fv = __builtin_nontemporal_load((const short8*)(G + gb));
        const short8 ov = __builtin_nontemporal_load((const short8*)(G + gb + HDIM));
        const short8 cv = __builtin_nontemporal_load((const short8*)(G + gb + 2 * HDIM));
        const f32x4 cp0 = __builtin_nontemporal_load((const f32x4*)(c_prev + (int64_t)m * HDIM + n));
        const f32x4 cp1 = __builtin_nontemporal_load((const f32x4*)(c_prev + (int64_t)m * HDIM + n + 4));
        float cp[8] = {cp0[0], cp0[1], cp0[2], cp0[3], cp1[0], cp1[1], cp1[2], cp1[3]};
        float hr[8], cr[8];
#pragma unroll
        for (int j = 0; j < 8; ++j) {
            const float fpre = bf2f((uint16_t)fv[j]) + b_f[n + j];
            const float opre = bf2f((uint16_t)ov[j]) + b_o[n + j];
            const float cpre = bf2f((uint16_t)cv[j]) + b_c[n + j];
            const float ft = fast_sigmoid(fpre);
            const float ot = fast_sigmoid(opre);
            const float ch = fast_tanh(cpre);
            const float ct = ft * cp[j] + (1.0f - ft) * ch;
            hr[j] = ot * fast_tanh(ct);
            cr[j] = ct;
        }
        f32x4 h0 = {hr[0], hr[1], hr[2], hr[3]};
        f32x4 h1 = {hr[4], hr[5], hr[6], hr[7]};
        f32x4 c0 = {cr[0], cr[1], cr[2], cr[3]};
        f32x4 c1 = {cr[4], cr[5], cr[6], cr[7]};
        __builtin_nontemporal_store(h0, (f32x4*)(h_out + (int64_t)m * HDIM + n));
        __builtin_nontemporal_store(h1, (f32x4*)(h_out + (int64_t)m * HDIM + n + 4));
        __builtin_nontemporal_store(c0, (f32x4*)(c_out + (int64_t)m * HDIM + n));
        __builtin_nontemporal_store(c1, (f32x4*)(c_out + (int64_t)m * HDIM + n + 4));
    }
}

extern "C" void kernel_launch(void* const* d_in, const int* in_sizes, int n_in,
                              void* d_out, int out_size, void* d_ws, size_t ws_size,
                              hipStream_t stream) {
    const float* x_t   = (const float*)d_in[0];
    const float* h_t_1 = (const float*)d_in[1];
    const float* c_t_1 = (const float*)d_in[2];
    const float* W_f   = (const float*)d_in[3];
    const float* b_f   = (const float*)d_in[4];
    const float* W_o   = (const float*)d_in[5];
    const float* b_o   = (const float*)d_in[6];
    const float* W_c   = (const float*)d_in[7];
    const float* b_c   = (const float*)d_in[8];

    uint16_t* xh  = (uint16_t*)d_ws;                            // 64 MiB
    uint16_t* Wbf = xh + (size_t)BDIM * KDIM;                   // 48 MiB
    uint16_t* G   = Wbf + (size_t)NDIM * KDIM;                  // 96 MiB

    float* h_out = (float*)d_out;
    float* c_out = h_out + (size_t)BDIM * HDIM;

    cvt_all_kernel<<<2048, 256, 0, stream>>>(x_t, h_t_1, W_f, W_o, W_c, xh, Wbf);
    lstm_gemm4p_kernel<<<768, 512, 0, stream>>>(xh, Wbf, G);
    lstm_epi_kernel<<<2048, 256, 0, stream>>>(G, c_t_1, b_f, b_o, b_c,
                                              h_out, c_out);
}

// Round 11
// 464.976 us; speedup vs baseline: 1.2672x; 1.0606x over previous
//
#include <hip/hip_runtime.h>
#include <hip/hip_bf16.h>
#include <stdint.h>

#define BDIM 8192
#define HDIM 2048
#define KDIM 4096   // IN + H
#define NDIM 6144   // 3 * H

using f32x4  = __attribute__((ext_vector_type(4))) float;
using bf16x8 = __attribute__((ext_vector_type(8))) short;
using short8 = __attribute__((ext_vector_type(8))) short;

__device__ __forceinline__ uint16_t f2bf(float f) {
    union { float f; uint32_t u; } v;
    v.f = f;
    uint32_t r = v.u + 0x7fffu + ((v.u >> 16) & 1u);  // RNE
    return (uint16_t)(r >> 16);
}

__device__ __forceinline__ float bf2f(uint16_t u) {
    union { uint32_t u; float f; } v;
    v.u = ((uint32_t)u) << 16;
    return v.f;
}

__device__ __forceinline__ float fast_sigmoid(float x) {
    return 1.0f / (1.0f + __expf(-x));
}

__device__ __forceinline__ float fast_tanh(float x) {
    float ax = fabsf(x);
    float t = __expf(-2.0f * ax);
    float r = (1.0f - t) / (1.0f + t);
    return copysignf(r, x);
}

__device__ __forceinline__ short8 cvt8(f32x4 a, f32x4 b) {
    short8 o;
    o[0] = (short)f2bf(a[0]); o[1] = (short)f2bf(a[1]);
    o[2] = (short)f2bf(a[2]); o[3] = (short)f2bf(a[3]);
    o[4] = (short)f2bf(b[0]); o[5] = (short)f2bf(b[1]);
    o[6] = (short)f2bf(b[2]); o[7] = (short)f2bf(b[3]);
    return o;
}

// ---------------- fused conversion kernel (8 elems/thread/iter) ----------
// xh = concat(x,h) -> bf16 [8192][4096]; Wb = [W_f;W_o;W_c] -> bf16 [6144][4096]
#define XH_CH8 ((int64_t)BDIM * KDIM / 8)
#define W_CH8  ((int64_t)3 * HDIM * KDIM / 8)
#define PER_GATE ((int64_t)HDIM * KDIM)

__global__ void cvt_all_kernel(const float* __restrict__ x,
                               const float* __restrict__ h,
                               const float* __restrict__ Wf,
                               const float* __restrict__ Wo,
                               const float* __restrict__ Wc,
                               uint16_t* __restrict__ xh,
                               uint16_t* __restrict__ Wb) {
    const int64_t total = XH_CH8 + W_CH8;
    for (int64_t i = (int64_t)blockIdx.x * blockDim.x + threadIdx.x; i < total;
         i += (int64_t)gridDim.x * blockDim.x) {
        const float* src;
        uint16_t* dst;
        if (i < XH_CH8) {
            int64_t e = i << 3;
            int b = (int)(e >> 12);
            int k = (int)(e & 4095);
            src = (k < 2048) ? (x + (int64_t)b * 2048 + k)
                             : (h + (int64_t)b * 2048 + (k - 2048));
            dst = xh + e;
        } else {
            int64_t e = (i - XH_CH8) << 3;
            // gate select without 64-bit division
            int gate = (e >= 2 * PER_GATE) ? 2 : (e >= PER_GATE ? 1 : 0);
            int64_t rem = e - (int64_t)gate * PER_GATE;
            const float* w = (gate == 0) ? Wf : (gate == 1) ? Wo : Wc;
            src = w + rem;
            dst = Wb + e;
        }
        f32x4 v0 = *(const f32x4*)(src);
        f32x4 v1 = *(const f32x4*)(src + 4);
        *(short8*)dst = cvt8(v0, v1);
    }
}

// ---------------- 256x256 4-phase GEMM (32 MFMA / barrier) ---------------
// Round-7 kernel verbatim (best measured: 326 us, MfmaUtil 58%, 0 conflicts).
// 8 waves (2M x 4N), per-wave C = 128x64. BK=64. 8-slot LDS ring (128 KiB).
//   A slots: even tile h0->0 h1->1, odd tile h0->2 h1->3
//   B slots: even tile h0->4 h1->5, odd tile h0->6 h1->7
// 4 phases per iteration (2 K-tiles t0,t1), fragment-reuse, split MM in
// Q2/Q4 to recycle bF0 registers. WC4@Q2 and WC4@Q4 cover all reads
// (FIFO proof in round-6/7 journals). 2 waits + 4 barriers / 2 K-tiles.

#define STAGE_A(slot, t, h) do { \
    _Pragma("unroll") for (int q_ = 0; q_ < 2; ++q_) { \
        const int r_ = s_row[q_]; \
        const uint16_t* src_ = A + (int64_t)(m0 + ((r_ >> 6) << 7) + ((h) << 6) + (r_ & 63)) * KDIM + ((t) << 6) + s_kc[q_]; \
        __builtin_amdgcn_global_load_lds((__attribute__((address_space(1))) void*)(src_), \
            (__attribute__((address_space(3))) void*)(&lds[slot][(q_ * 512 + tid) * 8]), 16, 0, 0); \
    } } while (0)

#define STAGE_B(slot, t, h) do { \
    _Pragma("unroll") for (int q_ = 0; q_ < 2; ++q_) { \
        const int r_ = s_row[q_]; \
        const uint16_t* src_ = Wb + (int64_t)(n0 + ((r_ >> 5) << 6) + ((h) << 5) + (r_ & 31)) * KDIM + ((t) << 6) + s_kc[q_]; \
        __builtin_amdgcn_global_load_lds((__attribute__((address_space(1))) void*)(src_), \
            (__attribute__((address_space(3))) void*)(&lds[slot][(q_ * 512 + tid) * 8]), 16, 0, 0); \
    } } while (0)

// read logical (slot, srow, kchunk) with swizzle
#define RD(slot, srow, kc) \
    (*(const bf16x8*)((const char*)(&lds[0][0]) + ((slot) * 16384) + ((srow) * 128) + ((((kc) ^ ((srow) & 7))) * 16)))

#define RD_A(tp, h) do { \
    _Pragma("unroll") for (int kk = 0; kk < 2; ++kk) \
        _Pragma("unroll") for (int mf = 0; mf < 4; ++mf) \
            aF[kk][mf] = RD((((tp) & 1) << 1) + (h), wm * 64 + mf * 16 + fr, kk * 4 + kg); \
} while (0)

#define RD_B(dst, tp, h) do { \
    _Pragma("unroll") for (int kk = 0; kk < 2; ++kk) \
        _Pragma("unroll") for (int nf = 0; nf < 2; ++nf) \
            dst[kk][nf] = RD(4 + (((tp) & 1) << 1) + (h), wn * 32 + nf * 16 + fr, kk * 4 + kg); \
} while (0)

#define MM(qm, qn, bsrc) do { \
    _Pragma("unroll") for (int kk = 0; kk < 2; ++kk) \
        _Pragma("unroll") for (int mf = 0; mf < 4; ++mf) \
            _Pragma("unroll") for (int nf = 0; nf < 2; ++nf) \
                acc[(qm) * 4 + mf][(qn) * 2 + nf] = __builtin_amdgcn_mfma_f32_16x16x32_bf16( \
                    aF[kk][mf], bsrc[kk][nf], acc[(qm) * 4 + mf][(qn) * 2 + nf], 0, 0, 0); \
} while (0)

#define PH4(READS1, STAGE, MM1, READS2, MM2, WAITC) do { \
    asm volatile("" ::: "memory"); \
    READS1; \
    STAGE; \
    asm volatile("" ::: "memory"); \
    __builtin_amdgcn_s_setprio(1); \
    MM1; \
    __builtin_amdgcn_s_setprio(0); \
    asm volatile("" ::: "memory"); \
    READS2; \
    asm volatile("" ::: "memory"); \
    __builtin_amdgcn_s_setprio(1); \
    MM2; \
    __builtin_amdgcn_s_setprio(0); \
    WAITC; \
    __builtin_amdgcn_s_barrier(); \
} while (0)

#define WC4 asm volatile("s_waitcnt vmcnt(4)" ::: "memory")
#define WC0 asm volatile("s_waitcnt vmcnt(0)" ::: "memory")

__global__ __launch_bounds__(512, 2) void lstm_gemm4p_kernel(
    const uint16_t* __restrict__ A,
    const uint16_t* __restrict__ Wb,
    uint16_t* __restrict__ G) {
    __shared__ uint16_t lds[8][8192];  // 128 KiB

    const int tid = threadIdx.x;
    const int lane = tid & 63;
    const int kg = lane >> 4;
    const int fr = lane & 15;
    const int wid = tid >> 6;
    const int wm = wid >> 2;   // 0..1
    const int wn = wid & 3;    // 0..3

    // XCD-aware swizzle: 768 blocks, 768 % 8 == 0 -> simple bijection
    const int bid = blockIdx.x;
    const int swz = (bid & 7) * 96 + (bid >> 3);
    const int mb = swz / 24;
    const int nb = swz - mb * 24;
    const int m0 = mb << 8;
    const int n0 = nb << 8;

    // staging constants: chunk = q*512 + tid -> row, swizzled k-chunk
    int s_row[2], s_kc[2];
#pragma unroll
    for (int q_ = 0; q_ < 2; ++q_) {
        const int chunk = q_ * 512 + tid;
        const int r_ = chunk >> 3;
        const int c_ = chunk & 7;
        s_row[q_] = r_;
        s_kc[q_] = (c_ ^ (r_ & 7)) * 8;  // element offset
    }

    f32x4 acc[8][4] = {};
    bf16x8 aF[2][4];
    bf16x8 bF0[2][2];
    bf16x8 bF1[2][2];

    // prologue: s4(B0h0),s0(A0h0),s5(B0h1),s1(A0h1),s6(B1h0) must complete;
    // s2(A1h0),s7(B1h1) may stay in flight (covered by WC4@Q2 of iter 0).
    STAGE_B(4, 0, 0); STAGE_A(0, 0, 0); STAGE_B(5, 0, 1);
    STAGE_A(1, 0, 1); STAGE_B(6, 1, 0);
    STAGE_A(2, 1, 0); STAGE_B(7, 1, 1);
    WC4;  // completes s4,s0,s5,s1,s6; leaves s2,s7 in flight
    __builtin_amdgcn_s_barrier();
    RD_B(bF0, 0, 0);  // pre-read B(0,h0) from s4
    asm volatile("s_waitcnt lgkmcnt(0)" ::: "memory");
    __builtin_amdgcn_s_barrier();  // s4 safe to re-stage from Q1 on

    // 64 K-tiles, 2 per iteration; i=31 is the peeled tail
    for (int i = 0; i < 31; ++i) {
        const int t0 = 2 * i;
        const int t1 = t0 + 1, t2 = t0 + 2, t3 = t0 + 3;
        PH4(RD_A(t0, 0); RD_B(bF1, t0, 1),
            STAGE_A(3, t1, 1); STAGE_B(4, t2, 0),
            MM(0, 0, bF0); MM(0, 1, bF1), ;, ;, );
        PH4(RD_A(t0, 1),
            STAGE_A(0, t2, 0); STAGE_B(5, t2, 1),
            MM(1, 0, bF0), RD_B(bF0, t1, 0), MM(1, 1, bF1), WC4);
        PH4(RD_A(t1, 0); RD_B(bF1, t1, 1),
            STAGE_A(1, t2, 1); STAGE_B(6, t3, 0),
            MM(0, 0, bF0); MM(0, 1, bF1), ;, ;, );
        PH4(RD_A(t1, 1),
            STAGE_A(2, t3, 0); STAGE_B(7, t3, 1),
            MM(1, 0, bF0), RD_B(bF0, t2, 0), MM(1, 1, bF1), WC4);
    }
    // tail: t0=62, t1=63; stages beyond K dropped; WC0 drains {s2,s7,s3}
    PH4(RD_A(62, 0); RD_B(bF1, 62, 1),
        STAGE_A(3, 63, 1),
        MM(0, 0, bF0); MM(0, 1, bF1), ;, ;, );
    PH4(RD_A(62, 1), ;,
        MM(1, 0, bF0), RD_B(bF0, 63, 0), MM(1, 1, bF1), WC0);
    PH4(RD_A(63, 0); RD_B(bF1, 63, 1), ;,
        MM(0, 0, bF0); MM(0, 1, bF1), ;, ;, );
    PH4(RD_A(63, 1), ;,
        MM(1, 0, bF0), ;, MM(1, 1, bF1), );

    // C-write: D layout col = lane&15, row = (lane>>4)*4 + j
#pragma unroll
    for (int mf = 0; mf < 8; ++mf) {
#pragma unroll
        for (int nf = 0; nf < 4; ++nf) {
            const int n = n0 + wn * 64 + nf * 16 + fr;
            const int64_t mbase = (int64_t)(m0 + wm * 128 + mf * 16 + kg * 4);
#pragma unroll
            for (int j = 0; j < 4; ++j) {
                G[(mbase + j) * NDIM + n] = f2bf(acc[mf][nf][j]);
            }
        }
    }
}

// ---------------- LSTM elementwise epilogue (plain vectorized I/O) -------

__global__ void lstm_epi_kernel(const uint16_t* __restrict__ G,
                                const float* __restrict__ c_prev,
                                const float* __restrict__ b_f,
                                const float* __restrict__ b_o,
                                const float* __restrict__ b_c,
                                float* __restrict__ h_out,
                                float* __restrict__ c_out) {
    const int64_t total = (int64_t)BDIM * HDIM / 8;
    for (int64_t i = (int64_t)blockIdx.x * blockDim.x + threadIdx.x; i < total;
         i += (int64_t)gridDim.x * blockDim.x) {
        const int64_t e = i << 3;
        const int m = (int)(e >> 11);
        const int n = (int)(e & 2047);
        const int64_t gb = (int64_t)m * NDIM + n;
        const short8 fv = *(const short8*)(G + gb);
        const short8 ov = *(const short8*)(G + gb + HDIM);
        const short8 cv = *(const short8*)(G + gb + 2 * HDIM);
        const f32x4 cp0 = *(const f32x4*)(c_prev + (int64_t)m * HDIM + n);
        const f32x4 cp1 = *(const f32x4*)(c_prev + (int64_t)m * HDIM + n + 4);
        float cp[8] = {cp0[0], cp0[1], cp0[2], cp0[3], cp1[0], cp1[1], cp1[2], cp1[3]};
        float hr[8], cr[8];
#pragma unroll
        for (int j = 0; j < 8; ++j) {
            const float fpre = bf2f((uint16_t)fv[j]) + b_f[n + j];
            const float opre = bf2f((uint16_t)ov[j]) + b_o[n + j];
            const float cpre = bf2f((uint16_t)cv[j]) + b_c[n + j];
            const float ft = fast_sigmoid(fpre);
            const float ot = fast_sigmoid(opre);
            const float ch = fast_tanh(cpre);
            const float ct = ft * cp[j] + (1.0f - ft) * ch;
            hr[j] = ot * fast_tanh(ct);
            cr[j] = ct;
        }
        f32x4 h0 = {hr[0], hr[1], hr[2], hr[3]};
        f32x4 h1 = {hr[4], hr[5], hr[6], hr[7]};
        f32x4 c0 = {cr[0], cr[1], cr[2], cr[3]};
        f32x4 c1 = {cr[4], cr[5], cr[6], cr[7]};
        *(f32x4*)(h_out + (int64_t)m * HDIM + n) = h0;
        *(f32x4*)(h_out + (int64_t)m * HDIM + n + 4) = h1;
        *(f32x4*)(c_out + (int64_t)m * HDIM + n) = c0;
        *(f32x4*)(c_out + (int64_t)m * HDIM + n + 4) = c1;
    }
}

extern "C" void kernel_launch(void* const* d_in, const int* in_sizes, int n_in,
                              void* d_out, int out_size, void* d_ws, size_t ws_size,
                              hipStream_t stream) {
    const float* x_t   = (const float*)d_in[0];
    const float* h_t_1 = (const float*)d_in[1];
    const float* c_t_1 = (const float*)d_in[2];
    const float* W_f   = (const float*)d_in[3];
    const float* b_f   = (const float*)d_in[4];
    const float* W_o   = (const float*)d_in[5];
    const float* b_o   = (const float*)d_in[6];
    const float* W_c   = (const float*)d_in[7];
    const float* b_c   = (const float*)d_in[8];

    uint16_t* xh  = (uint16_t*)d_ws;                            // 64 MiB
    uint16_t* Wbf = xh + (size_t)BDIM * KDIM;                   // 48 MiB
    uint16_t* G   = Wbf + (size_t)NDIM * KDIM;                  // 96 MiB

    float* h_out = (float*)d_out;
    float* c_out = h_out + (size_t)BDIM * HDIM;

    cvt_all_kernel<<<2048, 256, 0, stream>>>(x_t, h_t_1, W_f, W_o, W_c, xh, Wbf);
    lstm_gemm4p_kernel<<<768, 512, 0, stream>>>(xh, Wbf, G);
    lstm_epi_kernel<<<2048, 256, 0, stream>>>(G, c_t_1, b_f, b_o, b_c,
                                              h_out, c_out);
}

// Round 12
// 463.459 us; speedup vs baseline: 1.2714x; 1.0033x over previous
//
#include <hip/hip_runtime.h>
#include <hip/hip_bf16.h>
#include <stdint.h>

#define BDIM 8192
#define HDIM 2048
#define KDIM 4096   // IN + H
#define NDIM 6144   // 3 * H

using f32x4  = __attribute__((ext_vector_type(4))) float;
using bf16x8 = __attribute__((ext_vector_type(8))) short;
using short8 = __attribute__((ext_vector_type(8))) short;

__device__ __forceinline__ uint16_t f2bf(float f) {
    union { float f; uint32_t u; } v;
    v.f = f;
    uint32_t r = v.u + 0x7fffu + ((v.u >> 16) & 1u);  // RNE
    return (uint16_t)(r >> 16);
}

__device__ __forceinline__ float bf2f(uint16_t u) {
    union { uint32_t u; float f; } v;
    v.u = ((uint32_t)u) << 16;
    return v.f;
}

__device__ __forceinline__ float fast_sigmoid(float x) {
    return 1.0f / (1.0f + __expf(-x));
}

__device__ __forceinline__ float fast_tanh(float x) {
    float ax = fabsf(x);
    float t = __expf(-2.0f * ax);
    float r = (1.0f - t) / (1.0f + t);
    return copysignf(r, x);
}

__device__ __forceinline__ short8 cvt8(f32x4 a, f32x4 b) {
    short8 o;
    o[0] = (short)f2bf(a[0]); o[1] = (short)f2bf(a[1]);
    o[2] = (short)f2bf(a[2]); o[3] = (short)f2bf(a[3]);
    o[4] = (short)f2bf(b[0]); o[5] = (short)f2bf(b[1]);
    o[6] = (short)f2bf(b[2]); o[7] = (short)f2bf(b[3]);
    return o;
}

// ---------------- fused conversion kernel (8 elems/thread/iter) ----------
// xh = concat(x,h) -> bf16 [8192][4096]; Wb = [W_f;W_o;W_c] -> bf16 [6144][4096]
#define XH_CH8 ((int64_t)BDIM * KDIM / 8)
#define W_CH8  ((int64_t)3 * HDIM * KDIM / 8)
#define PER_GATE ((int64_t)HDIM * KDIM)

__global__ void cvt_all_kernel(const float* __restrict__ x,
                               const float* __restrict__ h,
                               const float* __restrict__ Wf,
                               const float* __restrict__ Wo,
                               const float* __restrict__ Wc,
                               uint16_t* __restrict__ xh,
                               uint16_t* __restrict__ Wb) {
    const int64_t total = XH_CH8 + W_CH8;
    for (int64_t i = (int64_t)blockIdx.x * blockDim.x + threadIdx.x; i < total;
         i += (int64_t)gridDim.x * blockDim.x) {
        const float* src;
        uint16_t* dst;
        if (i < XH_CH8) {
            int64_t e = i << 3;
            int b = (int)(e >> 12);
            int k = (int)(e & 4095);
            src = (k < 2048) ? (x + (int64_t)b * 2048 + k)
                             : (h + (int64_t)b * 2048 + (k - 2048));
            dst = xh + e;
        } else {
            int64_t e = (i - XH_CH8) << 3;
            // gate select without 64-bit division
            int gate = (e >= 2 * PER_GATE) ? 2 : (e >= PER_GATE ? 1 : 0);
            int64_t rem = e - (int64_t)gate * PER_GATE;
            const float* w = (gate == 0) ? Wf : (gate == 1) ? Wo : Wc;
            src = w + rem;
            dst = Wb + e;
        }
        f32x4 v0 = *(const f32x4*)(src);
        f32x4 v1 = *(const f32x4*)(src + 4);
        *(short8*)dst = cvt8(v0, v1);
    }
}

// ---------------- 256x256 4-phase GEMM (deep-latency waits) --------------
// Structure = round-7/11 gemm4p; ONLY the vmcnt schedule changed.
// Ring stage->read distance is 3 phases for every slot:
//   s0: staged Q2, read next-Q1 | s1,s6: Q3 -> next-Q2 | s2,s7: Q4 -> next-Q3
//   s3,s4: Q1 -> Q4 (same iter)
// Old waits (WC4 x2/iter) forced 1-phase-old loads to complete (~250 cyc
// issued-age vs ~600-900 cyc HBM latency -> stall every 2 phases).
// New: WC8 at EVERY phase end. FIFO walk (4 loads/phase):
//   invariant entering Q1: outstanding = {s1,s6,s2,s7} (8, last 2 phases).
//   Q1 rd s0,s5 (completed by prev Q4's WC8); +s3,s4 =12; WC8 -> s1,s6 done.
//   Q2 rd s1,s6; +s0,s5 =12; WC8 -> s2,s7 done.
//   Q3 rd s2,s7; +s1,s6 =12; WC8 -> s3,s4 done.
//   Q4 rd s3,s4; +s2,s7 =12; WC8 -> s0,s5 done; leaves {s1,s6,s2,s7}. QED.
// Every load now has 3 phases (~750+ cyc) before its completing wait.
// Prologue: 14 loads, WC8 completes s4,s0,s5 (needed immediately);
// tail waits WC6/WC2/WC0 (re-derived, header of tail below).

#define STAGE_A(slot, t, h) do { \
    _Pragma("unroll") for (int q_ = 0; q_ < 2; ++q_) { \
        const int r_ = s_row[q_]; \
        const uint16_t* src_ = A + (int64_t)(m0 + ((r_ >> 6) << 7) + ((h) << 6) + (r_ & 63)) * KDIM + ((t) << 6) + s_kc[q_]; \
        __builtin_amdgcn_global_load_lds((__attribute__((address_space(1))) void*)(src_), \
            (__attribute__((address_space(3))) void*)(&lds[slot][(q_ * 512 + tid) * 8]), 16, 0, 0); \
    } } while (0)

#define STAGE_B(slot, t, h) do { \
    _Pragma("unroll") for (int q_ = 0; q_ < 2; ++q_) { \
        const int r_ = s_row[q_]; \
        const uint16_t* src_ = Wb + (int64_t)(n0 + ((r_ >> 5) << 6) + ((h) << 5) + (r_ & 31)) * KDIM + ((t) << 6) + s_kc[q_]; \
        __builtin_amdgcn_global_load_lds((__attribute__((address_space(1))) void*)(src_), \
            (__attribute__((address_space(3))) void*)(&lds[slot][(q_ * 512 + tid) * 8]), 16, 0, 0); \
    } } while (0)

// read logical (slot, srow, kchunk) with swizzle
#define RD(slot, srow, kc) \
    (*(const bf16x8*)((const char*)(&lds[0][0]) + ((slot) * 16384) + ((srow) * 128) + ((((kc) ^ ((srow) & 7))) * 16)))

#define RD_A(tp, h) do { \
    _Pragma("unroll") for (int kk = 0; kk < 2; ++kk) \
        _Pragma("unroll") for (int mf = 0; mf < 4; ++mf) \
            aF[kk][mf] = RD((((tp) & 1) << 1) + (h), wm * 64 + mf * 16 + fr, kk * 4 + kg); \
} while (0)

#define RD_B(dst, tp, h) do { \
    _Pragma("unroll") for (int kk = 0; kk < 2; ++kk) \
        _Pragma("unroll") for (int nf = 0; nf < 2; ++nf) \
            dst[kk][nf] = RD(4 + (((tp) & 1) << 1) + (h), wn * 32 + nf * 16 + fr, kk * 4 + kg); \
} while (0)

#define MM(qm, qn, bsrc) do { \
    _Pragma("unroll") for (int kk = 0; kk < 2; ++kk) \
        _Pragma("unroll") for (int mf = 0; mf < 4; ++mf) \
            _Pragma("unroll") for (int nf = 0; nf < 2; ++nf) \
                acc[(qm) * 4 + mf][(qn) * 2 + nf] = __builtin_amdgcn_mfma_f32_16x16x32_bf16( \
                    aF[kk][mf], bsrc[kk][nf], acc[(qm) * 4 + mf][(qn) * 2 + nf], 0, 0, 0); \
} while (0)

#define PH4(READS1, STAGE, MM1, READS2, MM2, WAITC) do { \
    asm volatile("" ::: "memory"); \
    READS1; \
    STAGE; \
    asm volatile("" ::: "memory"); \
    __builtin_amdgcn_s_setprio(1); \
    MM1; \
    __builtin_amdgcn_s_setprio(0); \
    asm volatile("" ::: "memory"); \
    READS2; \
    asm volatile("" ::: "memory"); \
    __builtin_amdgcn_s_setprio(1); \
    MM2; \
    __builtin_amdgcn_s_setprio(0); \
    WAITC; \
    __builtin_amdgcn_s_barrier(); \
} while (0)

#define WC8 asm volatile("s_waitcnt vmcnt(8)" ::: "memory")
#define WC6 asm volatile("s_waitcnt vmcnt(6)" ::: "memory")
#define WC2 asm volatile("s_waitcnt vmcnt(2)" ::: "memory")
#define WC0 asm volatile("s_waitcnt vmcnt(0)" ::: "memory")

__global__ __launch_bounds__(512, 2) void lstm_gemm4p_kernel(
    const uint16_t* __restrict__ A,
    const uint16_t* __restrict__ Wb,
    uint16_t* __restrict__ G) {
    __shared__ uint16_t lds[8][8192];  // 128 KiB

    const int tid = threadIdx.x;
    const int lane = tid & 63;
    const int kg = lane >> 4;
    const int fr = lane & 15;
    const int wid = tid >> 6;
    const int wm = wid >> 2;   // 0..1
    const int wn = wid & 3;    // 0..3

    // XCD-aware swizzle: 768 blocks, 768 % 8 == 0 -> simple bijection
    const int bid = blockIdx.x;
    const int swz = (bid & 7) * 96 + (bid >> 3);
    const int mb = swz / 24;
    const int nb = swz - mb * 24;
    const int m0 = mb << 8;
    const int n0 = nb << 8;

    // staging constants: chunk = q*512 + tid -> row, swizzled k-chunk
    int s_row[2], s_kc[2];
#pragma unroll
    for (int q_ = 0; q_ < 2; ++q_) {
        const int chunk = q_ * 512 + tid;
        const int r_ = chunk >> 3;
        const int c_ = chunk & 7;
        s_row[q_] = r_;
        s_kc[q_] = (c_ ^ (r_ & 7)) * 8;  // element offset
    }

    f32x4 acc[8][4] = {};
    bf16x8 aF[2][4];
    bf16x8 bF0[2][2];
    bf16x8 bF1[2][2];

    // prologue (14 loads, FIFO oldest->newest):
    // s4(2),s0(2),s5(2),s1(2),s6(2),s2(2),s7(2)
    STAGE_B(4, 0, 0); STAGE_A(0, 0, 0); STAGE_B(5, 0, 1);
    STAGE_A(1, 0, 1); STAGE_B(6, 1, 0);
    STAGE_A(2, 1, 0); STAGE_B(7, 1, 1);
    WC8;  // completes s4,s0,s5 (loads 1-6); leaves {s1,s6,s2,s7} = invariant
    __builtin_amdgcn_s_barrier();
    RD_B(bF0, 0, 0);  // pre-read B(0,h0) from s4 (complete)
    asm volatile("s_waitcnt lgkmcnt(0)" ::: "memory");
    __builtin_amdgcn_s_barrier();  // s4 safe to re-stage from Q1 on

    // 64 K-tiles, 2 per iteration; i=31 is the peeled tail
    for (int i = 0; i < 31; ++i) {
        const int t0 = 2 * i;
        const int t1 = t0 + 1, t2 = t0 + 2, t3 = t0 + 3;
        PH4(RD_A(t0, 0); RD_B(bF1, t0, 1),
            STAGE_A(3, t1, 1); STAGE_B(4, t2, 0),
            MM(0, 0, bF0); MM(0, 1, bF1), ;, ;, WC8);
        PH4(RD_A(t0, 1),
            STAGE_A(0, t2, 0); STAGE_B(5, t2, 1),
            MM(1, 0, bF0), RD_B(bF0, t1, 0), MM(1, 1, bF1), WC8);
        PH4(RD_A(t1, 0); RD_B(bF1, t1, 1),
            STAGE_A(1, t2, 1); STAGE_B(6, t3, 0),
            MM(0, 0, bF0); MM(0, 1, bF1), ;, ;, WC8);
        PH4(RD_A(t1, 1),
            STAGE_A(2, t3, 0); STAGE_B(7, t3, 1),
            MM(1, 0, bF0), RD_B(bF0, t2, 0), MM(1, 1, bF1), WC8);
    }
    // tail: t0=62, t1=63. Entering outstanding = {s1,s6(Q3), s2,s7(Q4)} = 8.
    // T1 rd s0,s5 (completed by loop Q4 WC8); stage s3 (+2 -> 10);
    //    WC6 completes s1,s6 (for T2); leaves {s2,s7,s3}.
    // T2 rd s1,s6; WC2 completes s2,s7 (for T3); leaves {s3}.
    // T3 rd s2,s7; WC0 completes s3 (for T4).
    // T4 rd s3.
    PH4(RD_A(62, 0); RD_B(bF1, 62, 1),
        STAGE_A(3, 63, 1),
        MM(0, 0, bF0); MM(0, 1, bF1), ;, ;, WC6);
    PH4(RD_A(62, 1), ;,
        MM(1, 0, bF0), RD_B(bF0, 63, 0), MM(1, 1, bF1), WC2);
    PH4(RD_A(63, 0); RD_B(bF1, 63, 1), ;,
        MM(0, 0, bF0); MM(0, 1, bF1), ;, ;, WC0);
    PH4(RD_A(63, 1), ;,
        MM(1, 0, bF0), ;, MM(1, 1, bF1), );

    // C-write: D layout col = lane&15, row = (lane>>4)*4 + j
#pragma unroll
    for (int mf = 0; mf < 8; ++mf) {
#pragma unroll
        for (int nf = 0; nf < 4; ++nf) {
            const int n = n0 + wn * 64 + nf * 16 + fr;
            const int64_t mbase = (int64_t)(m0 + wm * 128 + mf * 16 + kg * 4);
#pragma unroll
            for (int j = 0; j < 4; ++j) {
                G[(mbase + j) * NDIM + n] = f2bf(acc[mf][nf][j]);
            }
        }
    }
}

// ---------------- LSTM elementwise epilogue (plain vectorized I/O) -------

__global__ void lstm_epi_kernel(const uint16_t* __restrict__ G,
                                const float* __restrict__ c_prev,
                                const float* __restrict__ b_f,
                                const float* __restrict__ b_o,
                                const float* __restrict__ b_c,
                                float* __restrict__ h_out,
                                float* __restrict__ c_out) {
    const int64_t total = (int64_t)BDIM * HDIM / 8;
    for (int64_t i = (int64_t)blockIdx.x * blockDim.x + threadIdx.x; i < total;
         i += (int64_t)gridDim.x * blockDim.x) {
        const int64_t e = i << 3;
        const int m = (int)(e >> 11);
        const int n = (int)(e & 2047);
        const int64_t gb = (int64_t)m * NDIM + n;
        const short8 fv = *(const short8*)(G + gb);
        const short8 ov = *(const short8*)(G + gb + HDIM);
        const short8 cv = *(const short8*)(G + gb + 2 * HDIM);
        const f32x4 cp0 = *(const f32x4*)(c_prev + (int64_t)m * HDIM + n);
        const f32x4 cp1 = *(const f32x4*)(c_prev + (int64_t)m * HDIM + n + 4);
        float cp[8] = {cp0[0], cp0[1], cp0[2], cp0[3], cp1[0], cp1[1], cp1[2], cp1[3]};
        float hr[8], cr[8];
#pragma unroll
        for (int j = 0; j < 8; ++j) {
            const float fpre = bf2f((uint16_t)fv[j]) + b_f[n + j];
            const float opre = bf2f((uint16_t)ov[j]) + b_o[n + j];
            const float cpre = bf2f((uint16_t)cv[j]) + b_c[n + j];
            const float ft = fast_sigmoid(fpre);
            const float ot = fast_sigmoid(opre);
            const float ch = fast_tanh(cpre);
            const float ct = ft * cp[j] + (1.0f - ft) * ch;
            hr[j] = ot * fast_tanh(ct);
            cr[j] = ct;
        }
        f32x4 h0 = {hr[0], hr[1], hr[2], hr[3]};
        f32x4 h1 = {hr[4], hr[5], hr[6], hr[7]};
        f32x4 c0 = {cr[0], cr[1], cr[2], cr[3]};
        f32x4 c1 = {cr[4], cr[5], cr[6], cr[7]};
        *(f32x4*)(h_out + (int64_t)m * HDIM + n) = h0;
        *(f32x4*)(h_out + (int64_t)m * HDIM + n + 4) = h1;
        *(f32x4*)(c_out + (int64_t)m * HDIM + n) = c0;
        *(f32x4*)(c_out + (int64_t)m * HDIM + n + 4) = c1;
    }
}

extern "C" void kernel_launch(void* const* d_in, const int* in_sizes, int n_in,
                              void* d_out, int out_size, void* d_ws, size_t ws_size,
                              hipStream_t stream) {
    const float* x_t   = (const float*)d_in[0];
    const float* h_t_1 = (const float*)d_in[1];
    const float* c_t_1 = (const float*)d_in[2];
    const float* W_f   = (const float*)d_in[3];
    const float* b_f   = (const float*)d_in[4];
    const float* W_o   = (const float*)d_in[5];
    const float* b_o   = (const float*)d_in[6];
    const float* W_c   = (const float*)d_in[7];
    const float* b_c   = (const float*)d_in[8];

    uint16_t* xh  = (uint16_t*)d_ws;                            // 64 MiB
    uint16_t* Wbf = xh + (size_t)BDIM * KDIM;                   // 48 MiB
    uint16_t* G   = Wbf + (size_t)NDIM * KDIM;                  // 96 MiB

    float* h_out = (float*)d_out;
    float* c_out = h_out + (size_t)BDIM * HDIM;

    cvt_all_kernel<<<2048, 256, 0, stream>>>(x_t, h_t_1, W_f, W_o, W_c, xh, Wbf);
    lstm_gemm4p_kernel<<<768, 512, 0, stream>>>(xh, Wbf, G);
    lstm_epi_kernel<<<2048, 256, 0, stream>>>(G, c_t_1, b_f, b_o, b_c,
                                              h_out, c_out);
}

// Round 13
// 441.211 us; speedup vs baseline: 1.3355x; 1.0504x over previous
//
#include <hip/hip_runtime.h>
#include <hip/hip_bf16.h>
#include <stdint.h>

#define BDIM 8192
#define HDIM 2048
#define KDIM 4096   // IN + H
#define NDIM 6144   // 3 * H

using f32x4  = __attribute__((ext_vector_type(4))) float;
using bf16x8 = __attribute__((ext_vector_type(8))) short;
using short8 = __attribute__((ext_vector_type(8))) short;

__device__ __forceinline__ uint16_t f2bf(float f) {
    union { float f; uint32_t u; } v;
    v.f = f;
    uint32_t r = v.u + 0x7fffu + ((v.u >> 16) & 1u);  // RNE
    return (uint16_t)(r >> 16);
}

__device__ __forceinline__ float bf2f(uint16_t u) {
    union { uint32_t u; float f; } v;
    v.u = ((uint32_t)u) << 16;
    return v.f;
}

__device__ __forceinline__ float fast_sigmoid(float x) {
    return 1.0f / (1.0f + __expf(-x));
}

__device__ __forceinline__ float fast_tanh(float x) {
    float ax = fabsf(x);
    float t = __expf(-2.0f * ax);
    float r = (1.0f - t) / (1.0f + t);
    return copysignf(r, x);
}

__device__ __forceinline__ short8 cvt8(f32x4 a, f32x4 b) {
    short8 o;
    o[0] = (short)f2bf(a[0]); o[1] = (short)f2bf(a[1]);
    o[2] = (short)f2bf(a[2]); o[3] = (short)f2bf(a[3]);
    o[4] = (short)f2bf(b[0]); o[5] = (short)f2bf(b[1]);
    o[6] = (short)f2bf(b[2]); o[7] = (short)f2bf(b[3]);
    return o;
}

// ---------------- fused conversion kernel (8 elems/thread/iter) ----------
// xh = concat(x,h) -> bf16 [8192][4096]; Wb = [W_f;W_o;W_c] -> bf16 [6144][4096]
#define XH_CH8 ((int64_t)BDIM * KDIM / 8)
#define W_CH8  ((int64_t)3 * HDIM * KDIM / 8)
#define PER_GATE ((int64_t)HDIM * KDIM)

__global__ void cvt_all_kernel(const float* __restrict__ x,
                               const float* __restrict__ h,
                               const float* __restrict__ Wf,
                               const float* __restrict__ Wo,
                               const float* __restrict__ Wc,
                               uint16_t* __restrict__ xh,
                               uint16_t* __restrict__ Wb) {
    const int64_t total = XH_CH8 + W_CH8;
    for (int64_t i = (int64_t)blockIdx.x * blockDim.x + threadIdx.x; i < total;
         i += (int64_t)gridDim.x * blockDim.x) {
        const float* src;
        uint16_t* dst;
        if (i < XH_CH8) {
            int64_t e = i << 3;
            int b = (int)(e >> 12);
            int k = (int)(e & 4095);
            src = (k < 2048) ? (x + (int64_t)b * 2048 + k)
                             : (h + (int64_t)b * 2048 + (k - 2048));
            dst = xh + e;
        } else {
            int64_t e = (i - XH_CH8) << 3;
            // gate select without 64-bit division
            int gate = (e >= 2 * PER_GATE) ? 2 : (e >= PER_GATE ? 1 : 0);
            int64_t rem = e - (int64_t)gate * PER_GATE;
            const float* w = (gate == 0) ? Wf : (gate == 1) ? Wo : Wc;
            src = w + rem;
            dst = Wb + e;
        }
        f32x4 v0 = *(const f32x4*)(src);
        f32x4 v1 = *(const f32x4*)(src + 4);
        *(short8*)dst = cvt8(v0, v1);
    }
}

// ---------------- 256x256 4-phase GEMM (cohort-localized swizzle) --------
// Structure = round-12 gemm4p (deep WC8 waits); ONLY the blockIdx->tile
// mapping changed. Old: each concurrent cohort touched all 24 nb -> full
// 48 MiB W streamed per round -> L3 thrash -> staging loads miss to HBM
// (~900 cyc) right at the vmcnt slack boundary (~750-900 cyc) -> stalls.
// New bijective map (768 = 8 XCD x 96):
//   x = bid & 7 (XCD), l = bid >> 3 in [0,96)
//   mb = x*4 + ((l>>3)&3)        (4-mb band per XCD, as before)
//   nb = ((l>>5)<<3) + (l&7)     (8-nb slice per 32-block phase)
// Cohort working set: A 64 MiB + W-slice 16 MiB = 80 MiB << 256 MiB L3;
// each mb-panel's 8 nb-blocks are consecutive l -> concurrent on one XCD
// (A L2/L3-hot). Re-reads become cache hits (~200-400 cyc << slack).

#define STAGE_A(slot, t, h) do { \
    _Pragma("unroll") for (int q_ = 0; q_ < 2; ++q_) { \
        const int r_ = s_row[q_]; \
        const uint16_t* src_ = A + (int64_t)(m0 + ((r_ >> 6) << 7) + ((h) << 6) + (r_ & 63)) * KDIM + ((t) << 6) + s_kc[q_]; \
        __builtin_amdgcn_global_load_lds((__attribute__((address_space(1))) void*)(src_), \
            (__attribute__((address_space(3))) void*)(&lds[slot][(q_ * 512 + tid) * 8]), 16, 0, 0); \
    } } while (0)

#define STAGE_B(slot, t, h) do { \
    _Pragma("unroll") for (int q_ = 0; q_ < 2; ++q_) { \
        const int r_ = s_row[q_]; \
        const uint16_t* src_ = Wb + (int64_t)(n0 + ((r_ >> 5) << 6) + ((h) << 5) + (r_ & 31)) * KDIM + ((t) << 6) + s_kc[q_]; \
        __builtin_amdgcn_global_load_lds((__attribute__((address_space(1))) void*)(src_), \
            (__attribute__((address_space(3))) void*)(&lds[slot][(q_ * 512 + tid) * 8]), 16, 0, 0); \
    } } while (0)

// read logical (slot, srow, kchunk) with swizzle
#define RD(slot, srow, kc) \
    (*(const bf16x8*)((const char*)(&lds[0][0]) + ((slot) * 16384) + ((srow) * 128) + ((((kc) ^ ((srow) & 7))) * 16)))

#define RD_A(tp, h) do { \
    _Pragma("unroll") for (int kk = 0; kk < 2; ++kk) \
        _Pragma("unroll") for (int mf = 0; mf < 4; ++mf) \
            aF[kk][mf] = RD((((tp) & 1) << 1) + (h), wm * 64 + mf * 16 + fr, kk * 4 + kg); \
} while (0)

#define RD_B(dst, tp, h) do { \
    _Pragma("unroll") for (int kk = 0; kk < 2; ++kk) \
        _Pragma("unroll") for (int nf = 0; nf < 2; ++nf) \
            dst[kk][nf] = RD(4 + (((tp) & 1) << 1) + (h), wn * 32 + nf * 16 + fr, kk * 4 + kg); \
} while (0)

#define MM(qm, qn, bsrc) do { \
    _Pragma("unroll") for (int kk = 0; kk < 2; ++kk) \
        _Pragma("unroll") for (int mf = 0; mf < 4; ++mf) \
            _Pragma("unroll") for (int nf = 0; nf < 2; ++nf) \
                acc[(qm) * 4 + mf][(qn) * 2 + nf] = __builtin_amdgcn_mfma_f32_16x16x32_bf16( \
                    aF[kk][mf], bsrc[kk][nf], acc[(qm) * 4 + mf][(qn) * 2 + nf], 0, 0, 0); \
} while (0)

#define PH4(READS1, STAGE, MM1, READS2, MM2, WAITC) do { \
    asm volatile("" ::: "memory"); \
    READS1; \
    STAGE; \
    asm volatile("" ::: "memory"); \
    __builtin_amdgcn_s_setprio(1); \
    MM1; \
    __builtin_amdgcn_s_setprio(0); \
    asm volatile("" ::: "memory"); \
    READS2; \
    asm volatile("" ::: "memory"); \
    __builtin_amdgcn_s_setprio(1); \
    MM2; \
    __builtin_amdgcn_s_setprio(0); \
    WAITC; \
    __builtin_amdgcn_s_barrier(); \
} while (0)

#define WC8 asm volatile("s_waitcnt vmcnt(8)" ::: "memory")
#define WC6 asm volatile("s_waitcnt vmcnt(6)" ::: "memory")
#define WC2 asm volatile("s_waitcnt vmcnt(2)" ::: "memory")
#define WC0 asm volatile("s_waitcnt vmcnt(0)" ::: "memory")

__global__ __launch_bounds__(512, 2) void lstm_gemm4p_kernel(
    const uint16_t* __restrict__ A,
    const uint16_t* __restrict__ Wb,
    uint16_t* __restrict__ G) {
    __shared__ uint16_t lds[8][8192];  // 128 KiB

    const int tid = threadIdx.x;
    const int lane = tid & 63;
    const int kg = lane >> 4;
    const int fr = lane & 15;
    const int wid = tid >> 6;
    const int wm = wid >> 2;   // 0..1
    const int wn = wid & 3;    // 0..3

    // cohort-localized XCD swizzle (bijective: 8 XCD x 3 phases x 4 mb x 8 nb)
    const int bid = blockIdx.x;
    const int xcd = bid & 7;
    const int l = bid >> 3;                    // 0..95
    const int mb = xcd * 4 + ((l >> 3) & 3);   // 0..31
    const int nb = ((l >> 5) << 3) + (l & 7);  // 0..23
    const int m0 = mb << 8;
    const int n0 = nb << 8;

    // staging constants: chunk = q*512 + tid -> row, swizzled k-chunk
    int s_row[2], s_kc[2];
#pragma unroll
    for (int q_ = 0; q_ < 2; ++q_) {
        const int chunk = q_ * 512 + tid;
        const int r_ = chunk >> 3;
        const int c_ = chunk & 7;
        s_row[q_] = r_;
        s_kc[q_] = (c_ ^ (r_ & 7)) * 8;  // element offset
    }

    f32x4 acc[8][4] = {};
    bf16x8 aF[2][4];
    bf16x8 bF0[2][2];
    bf16x8 bF1[2][2];

    // prologue (14 loads, FIFO oldest->newest):
    // s4(2),s0(2),s5(2),s1(2),s6(2),s2(2),s7(2)
    STAGE_B(4, 0, 0); STAGE_A(0, 0, 0); STAGE_B(5, 0, 1);
    STAGE_A(1, 0, 1); STAGE_B(6, 1, 0);
    STAGE_A(2, 1, 0); STAGE_B(7, 1, 1);
    WC8;  // completes s4,s0,s5 (loads 1-6); leaves {s1,s6,s2,s7} = invariant
    __builtin_amdgcn_s_barrier();
    RD_B(bF0, 0, 0);  // pre-read B(0,h0) from s4 (complete)
    asm volatile("s_waitcnt lgkmcnt(0)" ::: "memory");
    __builtin_amdgcn_s_barrier();  // s4 safe to re-stage from Q1 on

    // 64 K-tiles, 2 per iteration; i=31 is the peeled tail
    for (int i = 0; i < 31; ++i) {
        const int t0 = 2 * i;
        const int t1 = t0 + 1, t2 = t0 + 2, t3 = t0 + 3;
        PH4(RD_A(t0, 0); RD_B(bF1, t0, 1),
            STAGE_A(3, t1, 1); STAGE_B(4, t2, 0),
            MM(0, 0, bF0); MM(0, 1, bF1), ;, ;, WC8);
        PH4(RD_A(t0, 1),
            STAGE_A(0, t2, 0); STAGE_B(5, t2, 1),
            MM(1, 0, bF0), RD_B(bF0, t1, 0), MM(1, 1, bF1), WC8);
        PH4(RD_A(t1, 0); RD_B(bF1, t1, 1),
            STAGE_A(1, t2, 1); STAGE_B(6, t3, 0),
            MM(0, 0, bF0); MM(0, 1, bF1), ;, ;, WC8);
        PH4(RD_A(t1, 1),
            STAGE_A(2, t3, 0); STAGE_B(7, t3, 1),
            MM(1, 0, bF0), RD_B(bF0, t2, 0), MM(1, 1, bF1), WC8);
    }
    // tail: t0=62, t1=63. Entering outstanding = {s1,s6(Q3), s2,s7(Q4)} = 8.
    // T1 rd s0,s5 (completed by loop Q4 WC8); stage s3 (+2 -> 10);
    //    WC6 completes s1,s6 (for T2); leaves {s2,s7,s3}.
    // T2 rd s1,s6; WC2 completes s2,s7 (for T3); leaves {s3}.
    // T3 rd s2,s7; WC0 completes s3 (for T4).
    // T4 rd s3.
    PH4(RD_A(62, 0); RD_B(bF1, 62, 1),
        STAGE_A(3, 63, 1),
        MM(0, 0, bF0); MM(0, 1, bF1), ;, ;, WC6);
    PH4(RD_A(62, 1), ;,
        MM(1, 0, bF0), RD_B(bF0, 63, 0), MM(1, 1, bF1), WC2);
    PH4(RD_A(63, 0); RD_B(bF1, 63, 1), ;,
        MM(0, 0, bF0); MM(0, 1, bF1), ;, ;, WC0);
    PH4(RD_A(63, 1), ;,
        MM(1, 0, bF0), ;, MM(1, 1, bF1), );

    // C-write: D layout col = lane&15, row = (lane>>4)*4 + j
#pragma unroll
    for (int mf = 0; mf < 8; ++mf) {
#pragma unroll
        for (int nf = 0; nf < 4; ++nf) {
            const int n = n0 + wn * 64 + nf * 16 + fr;
            const int64_t mbase = (int64_t)(m0 + wm * 128 + mf * 16 + kg * 4);
#pragma unroll
            for (int j = 0; j < 4; ++j) {
                G[(mbase + j) * NDIM + n] = f2bf(acc[mf][nf][j]);
            }
        }
    }
}

// ---------------- LSTM elementwise epilogue (plain vectorized I/O) -------

__global__ void lstm_epi_kernel(const uint16_t* __restrict__ G,
                                const float* __restrict__ c_prev,
                                const float* __restrict__ b_f,
                                const float* __restrict__ b_o,
                                const float* __restrict__ b_c,
                                float* __restrict__ h_out,
                                float* __restrict__ c_out) {
    const int64_t total = (int64_t)BDIM * HDIM / 8;
    for (int64_t i = (int64_t)blockIdx.x * blockDim.x + threadIdx.x; i < total;
         i += (int64_t)gridDim.x * blockDim.x) {
        const int64_t e = i << 3;
        const int m = (int)(e >> 11);
        const int n = (int)(e & 2047);
        const int64_t gb = (int64_t)m * NDIM + n;
        const short8 fv = *(const short8*)(G + gb);
        const short8 ov = *(const short8*)(G + gb + HDIM);
        const short8 cv = *(const short8*)(G + gb + 2 * HDIM);
        const f32x4 cp0 = *(const f32x4*)(c_prev + (int64_t)m * HDIM + n);
        const f32x4 cp1 = *(const f32x4*)(c_prev + (int64_t)m * HDIM + n + 4);
        float cp[8] = {cp0[0], cp0[1], cp0[2], cp0[3], cp1[0], cp1[1], cp1[2], cp1[3]};
        float hr[8], cr[8];
#pragma unroll
        for (int j = 0; j < 8; ++j) {
            const float fpre = bf2f((uint16_t)fv[j]) + b_f[n + j];
            const float opre = bf2f((uint16_t)ov[j]) + b_o[n + j];
            const float cpre = bf2f((uint16_t)cv[j]) + b_c[n + j];
            const float ft = fast_sigmoid(fpre);
            const float ot = fast_sigmoid(opre);
            const float ch = fast_tanh(cpre);
            const float ct = ft * cp[j] + (1.0f - ft) * ch;
            hr[j] = ot * fast_tanh(ct);
            cr[j] = ct;
        }
        f32x4 h0 = {hr[0], hr[1], hr[2], hr[3]};
        f32x4 h1 = {hr[4], hr[5], hr[6], hr[7]};
        f32x4 c0 = {cr[0], cr[1], cr[2], cr[3]};
        f32x4 c1 = {cr[4], cr[5], cr[6], cr[7]};
        *(f32x4*)(h_out + (int64_t)m * HDIM + n) = h0;
        *(f32x4*)(h_out + (int64_t)m * HDIM + n + 4) = h1;
        *(f32x4*)(c_out + (int64_t)m * HDIM + n) = c0;
        *(f32x4*)(c_out + (int64_t)m * HDIM + n + 4) = c1;
    }
}

extern "C" void kernel_launch(void* const* d_in, const int* in_sizes, int n_in,
                              void* d_out, int out_size, void* d_ws, size_t ws_size,
                              hipStream_t stream) {
    const float* x_t   = (const float*)d_in[0];
    const float* h_t_1 = (const float*)d_in[1];
    const float* c_t_1 = (const float*)d_in[2];
    const float* W_f   = (const float*)d_in[3];
    const float* b_f   = (const float*)d_in[4];
    const float* W_o   = (const float*)d_in[5];
    const float* b_o   = (const float*)d_in[6];
    const float* W_c   = (const float*)d_in[7];
    const float* b_c   = (const float*)d_in[8];

    uint16_t* xh  = (uint16_t*)d_ws;                            // 64 MiB
    uint16_t* Wbf = xh + (size_t)BDIM * KDIM;                   // 48 MiB
    uint16_t* G   = Wbf + (size_t)NDIM * KDIM;                  // 96 MiB

    float* h_out = (float*)d_out;
    float* c_out = h_out + (size_t)BDIM * HDIM;

    cvt_all_kernel<<<2048, 256, 0, stream>>>(x_t, h_t_1, W_f, W_o, W_c, xh, Wbf);
    lstm_gemm4p_kernel<<<768, 512, 0, stream>>>(xh, Wbf, G);
    lstm_epi_kernel<<<2048, 256, 0, stream>>>(G, c_t_1, b_f, b_o, b_c,
                                              h_out, c_out);
}